// Round 22
// baseline (621.186 us; speedup 1.0000x reference)
//
#include <hip/hip_runtime.h>
#include <hip/hip_bf16.h>

// ---------------------------------------------------------------------------
// GCN via associativity:  spmm(H) @ W == spmm(H @ W), S = R(I+A)R.
// Weights FOLDED INTO OPERANDS: dense epilogue prescales each output row by
// rnorm[row] (free f32x4 load there), spmm is a pure gather-SUM finished by
// one x rnorm[r]. meta = col only (int) -> fill's random writes halve,
// spmm meta reads halve.
//   D0' = R·(X @ W0T)  (f16) ; A = gelu(rnorm*spmmsum(D0') + b0) -> TILED f16
//   D1' = R·(A @ W1T)  (f16) ; B = gelu(...b1) -> TILED f16
//   D2' = R·(B @ W2T)  (f16) ; out = rnorm*spmmsum(D2') + b2 (fp32)
// Dense on MFMA: A single f16, W = f16 hi + f16 lo -> 2 MFMA products.
// SpMM: multi-row waves (16B/lane, lanes-per-row=D/8): 1 gather instruction
// serves 2 (D=256) / 4 (D=128) edges. At the service floor: FETCH=402MB
// (XCD-replication compulsory) at ~3.8TB/s.
// ---------------------------------------------------------------------------

typedef float f32x4 __attribute__((ext_vector_type(4)));
typedef float f32x2 __attribute__((ext_vector_type(2)));
typedef _Float16 h16x8 __attribute__((ext_vector_type(8)));
typedef _Float16 h16x4 __attribute__((ext_vector_type(4)));

__device__ __forceinline__ float gelu_fast(float x) {
    float u = 0.7978845608028654f * (x + 0.044715f * x * x * x);
    return x / (1.0f + __expf(-2.0f * u));
}

// count + per-edge rank (removes the fill-pass atomic)
__global__ void count_kernel(const int* __restrict__ row, int* __restrict__ cnt,
                             int* __restrict__ rank, int e) {
    int i = blockIdx.x * blockDim.x + threadIdx.x;
    if (i < e) rank[i] = atomicAdd(&cnt[row[i]], 1);
}

// block scan over cnt (+ fused rnorm = rsqrt(deg+1))
__global__ void scan1_kernel(const int* __restrict__ cnt, int* __restrict__ rowptr,
                             int* __restrict__ bsum, float* __restrict__ rnorm, int n) {
    __shared__ int s[1024];
    int t = threadIdx.x;
    int i = blockIdx.x * 1024 + t;
    int v = (i < n) ? cnt[i] : 0;
    if (i < n) rnorm[i] = rsqrtf((float)(v + 1));
    s[t] = v;
    __syncthreads();
    for (int off = 1; off < 1024; off <<= 1) {
        int x = (t >= off) ? s[t - off] : 0;
        __syncthreads();
        s[t] += x;
        __syncthreads();
    }
    if (i < n) rowptr[i] = s[t] - v;
    if (t == 1023) bsum[blockIdx.x] = s[1023];
}

__global__ void scan2_kernel(int* bsum, int nb) {
    __shared__ int s[128];
    int t = threadIdx.x;
    int v = (t < nb) ? bsum[t] : 0;
    s[t] = v;
    __syncthreads();
    for (int off = 1; off < 128; off <<= 1) {
        int x = (t >= off) ? s[t - off] : 0;
        __syncthreads();
        s[t] += x;
        __syncthreads();
    }
    if (t < nb) bsum[t] = s[t] - v;   // exclusive
}

__global__ void scan3_kernel(int* __restrict__ rowptr, const int* __restrict__ bsum, int n, int e) {
    int i = blockIdx.x * blockDim.x + threadIdx.x;
    if (i < n) rowptr[i] += bsum[i >> 10];
    if (i == 0) rowptr[n] = e;
}

// atomic-free fill using precomputed ranks; col-only meta (4B/edge)
__global__ void fill_kernel(const int* __restrict__ row, const int* __restrict__ col,
                            const int* __restrict__ rank,
                            const int* __restrict__ rowptr,
                            int* __restrict__ metac, int e) {
    int i = blockIdx.x * blockDim.x + threadIdx.x;
    if (i >= e) return;
    metac[rowptr[row[i]] + rank[i]] = col[i];
}

// fp32 -> (f16 hi, f16 lo) for all three weight matrices in one launch
__global__ void splitW_kernel(const float* __restrict__ W0, const float* __restrict__ W1,
                              const float* __restrict__ W2,
                              _Float16* __restrict__ W0h, _Float16* __restrict__ W0l,
                              _Float16* __restrict__ W1h, _Float16* __restrict__ W1l,
                              _Float16* __restrict__ W2h, _Float16* __restrict__ W2l) {
    int i = blockIdx.x * blockDim.x + threadIdx.x;   // f32x4 group index, < 40960
    const float* src;
    _Float16 *dh, *dl;
    int j;
    if (i < 16384)      { src = W0; dh = W0h; dl = W0l; j = i; }
    else if (i < 32768) { src = W1; dh = W1h; dl = W1l; j = i - 16384; }
    else                { src = W2; dh = W2h; dl = W2l; j = i - 32768; }
    f32x4 x = *(const f32x4*)(src + (size_t)j * 4);
    h16x4 h, l;
#pragma unroll
    for (int q = 0; q < 4; ++q) {
        _Float16 hb = (_Float16)x[q];
        h[q] = hb;
        l[q] = (_Float16)(x[q] - (float)hb);
    }
    *(h16x4*)(dh + (size_t)j * 4) = h;
    *(h16x4*)(dl + (size_t)j * 4) = l;
}

// Multi-row waves: LPR = D/8 lanes per row (every lane gathers 16B = 8 f16);
// RPW = 64/LPR rows per wave. Pure SUM of prescaled rows; finish = x rnorm[r].
// Tail masked via computed 0/1 coefficient. SPLIT: LDS full-line tiled write.
template <int D, bool GELU, bool SPLIT>
__global__ __launch_bounds__(256) void spmm_kernel(const _Float16* __restrict__ in,
                                                   float* __restrict__ out,
                                                   _Float16* __restrict__ oat,
                                                   const int* __restrict__ rowptr,
                                                   const int* __restrict__ metac,
                                                   const float* __restrict__ rnorm,
                                                   const float* __restrict__ bias, int n) {
    constexpr int LPR = D / 8;           // lanes per row (32 / 16)
    constexpr int RPW = 64 / LPR;        // rows per wave  (2 / 4)
    constexpr int BR = 4 * RPW;          // rows per block (8 / 16)
    __shared__ _Float16 h_lds[8][256];   // used by SPLIT (D=256) only

    int t = threadIdx.x;
    int lane = t & 63;
    int w = t >> 6;
    int sub = lane % LPR;
    int rowsel = lane / LPR;
    int wid = blockIdx.x * BR + w * RPW + rowsel;
    if (wid >= n) wid = n - 1;           // safe clamp

    const _Float16* lanebase = in + sub * 8;
    float rn = rnorm[wid];
    float acc[8];
    {
        h16x8 a = *(const h16x8*)(lanebase + (size_t)wid * D);   // self (coef 1)
#pragma unroll
        for (int q = 0; q < 8; ++q) acc[q] = (float)a[q];
    }

    int e0 = rowptr[wid], e1 = rowptr[wid + 1];
    int ne = e1 - e0;
    int maxb = (ne + 3) >> 2;
    int elast = (e1 > e0) ? (e1 - 1) : 0;

    int mc[4];
    float mw[4];
    auto loadM = [&](int b) {
#pragma unroll
        for (int u = 0; u < 4; ++u) {
            int idx = e0 + b * 4 + u;
            bool val = idx < e1;
            mc[u] = metac[val ? idx : elast];
            mw[u] = val ? 1.0f : 0.0f;
        }
    };
    if (maxb > 0) loadM(0);
    for (int b = 0; b < maxb; ++b) {
        h16x8 v[4];
#pragma unroll
        for (int u = 0; u < 4; ++u)
            v[u] = *(const h16x8*)(lanebase + (size_t)mc[u] * D);
        float wts[4];
#pragma unroll
        for (int u = 0; u < 4; ++u) wts[u] = mw[u];
        if (b + 1 < maxb) loadM(b + 1);
#pragma unroll
        for (int u = 0; u < 4; ++u)
#pragma unroll
            for (int q = 0; q < 8; ++q) acc[q] = fmaf(wts[u], (float)v[u][q], acc[q]);
    }

    if (SPLIT) {
        f32x4 bv0 = *(const f32x4*)(bias + sub * 8);
        f32x4 bv1 = *(const f32x4*)(bias + sub * 8 + 4);
        h16x8 h;
#pragma unroll
        for (int q = 0; q < 4; ++q) {
            float x0 = acc[q] * rn + bv0[q];
            float x1 = acc[q + 4] * rn + bv1[q];
            h[q] = (_Float16)(GELU ? gelu_fast(x0) : x0);
            h[q + 4] = (_Float16)(GELU ? gelu_fast(x1) : x1);
        }
        *(h16x8*)&h_lds[w * 2 + rowsel][sub * 8] = h;
        __syncthreads();
        int kc = t >> 5;                 // 0..7
        int g  = (t >> 3) & 3;           // 0..3
        int j  = t & 7;                  // 0..7 (row within block)
        size_t rg = (size_t)(blockIdx.x >> 1);
        int half = blockIdx.x & 1;
        size_t toff = ((rg * 8 + kc) * 64 + g * 16 + half * 8 + j) * 8;
        __builtin_nontemporal_store(*(const h16x8*)&h_lds[j][kc * 32 + g * 8],
                                    (h16x8*)(oat + toff));
    } else {
        f32x4 bv0 = *(const f32x4*)(bias + sub * 8);
        f32x4 bv1 = *(const f32x4*)(bias + sub * 8 + 4);
        f32x4 o0, o1;
#pragma unroll
        for (int q = 0; q < 4; ++q) {
            float x0 = acc[q] * rn + bv0[q];
            float x1 = acc[q + 4] * rn + bv1[q];
            o0[q] = GELU ? gelu_fast(x0) : x0;
            o1[q] = GELU ? gelu_fast(x1) : x1;
        }
        float* dst = out + (size_t)wid * D + sub * 8;
        __builtin_nontemporal_store(o0, (f32x4*)dst);
        __builtin_nontemporal_store(o1, (f32x4*)(dst + 4));
    }
}

// out[N][DO](f16) = rnorm[row] * (A(f16) @ (Wh+Wl)(f16)^T), 2 f16 MFMAs.
// A source: XIN ? fp32 row-major X (in-register f16 convert) : tiled f16.
// COUNTED-vmcnt pipeline (T4), double-buffered LDS W staging.
template <int DO, int RT, bool XIN>
__global__ __launch_bounds__(256, 2) void dense_mfma_kernel(
        const _Float16* __restrict__ AT, const float* __restrict__ Xf,
        const _Float16* __restrict__ Whi, const _Float16* __restrict__ Wlo,
        const float* __restrict__ rnorm,
        _Float16* __restrict__ out, int n) {
    constexpr int KC = 32;
    constexpr int NCH = 256 / KC;        // 8 chunks
    constexpr int NTT = DO / 16;         // total col tiles (16 / 8)
    constexpr int NT = NTT / 2;          // col tiles per wave
    constexpr int NFRAG = 2 * NTT;       // Wh+Wl frags per chunk
    constexpr int BM = 2 * RT * 16;      // rows per block (128)
    __shared__ h16x8 s_w[2][NFRAG * 64]; // 2x32KB (DO=256) / 2x16KB (128)

    int t = threadIdx.x;
    int lane = t & 63;
    int w = t >> 6;
    int r = lane & 15;
    int g = lane >> 4;
    int h = w & 1;                       // col half
    int row0 = blockIdx.x * BM + (w >> 1) * (RT * 16);
    int n16 = (n + 15) >> 4;

    size_t argi[RT];                     // clamped row-group (tiled) or row (XIN)
#pragma unroll
    for (int rt = 0; rt < RT; ++rt) {
        if (XIN) {
            int arow = row0 + rt * 16 + r;
            if (arow >= n) arow = n - 1;
            argi[rt] = (size_t)arow;
        } else {
            int rg = (row0 >> 4) + rt;
            if (rg >= n16) rg = n16 - 1;
            argi[rt] = (size_t)rg;
        }
    }

    f32x4 acc[RT][NT];
#pragma unroll
    for (int rt = 0; rt < RT; ++rt)
#pragma unroll
        for (int nt = 0; nt < NT; ++nt) acc[rt][nt] = (f32x4){0.f, 0.f, 0.f, 0.f};

    auto stage = [&](int c, int b) {
#pragma unroll
        for (int i = 0; i < NFRAG / 4; ++i) {
            int s = t + i * 256;
            int sl = s & 63;
            int f = s >> 6;              // f = op*NTT + ntf
            int ntf = f % NTT;
            int op = f / NTT;
            const _Float16* src = op ? Wlo : Whi;
            const _Float16* gsrc =
                &src[(size_t)(ntf * 16 + (sl & 15)) * 256 + c * KC + ((sl >> 4) << 3)];
            __builtin_amdgcn_global_load_lds(
                (const __attribute__((address_space(1))) void*)gsrc,
                (__attribute__((address_space(3))) void*)&s_w[b][s], 16, 0, 0);
        }
    };

    h16x8 aC[2][RT];                     // 2-set A fragment file
    f32x4 nf[RT][2];                     // XIN raw fp32 in flight

    auto prefetchA = [&](int c, int set) {
#pragma unroll
        for (int rt = 0; rt < RT; ++rt) {
            if (XIN) {
                const float* src = &Xf[argi[rt] * 256 + c * KC + g * 8];
                nf[rt][0] = *(const f32x4*)src;
                nf[rt][1] = *(const f32x4*)(src + 4);
            } else {
                aC[set][rt] = *(const h16x8*)&AT[((argi[rt] * 8 + c) * 64 + lane) * 8];
            }
        }
    };
    auto commitA = [&](int set) {
        if (XIN) {
#pragma unroll
            for (int rt = 0; rt < RT; ++rt) {
                h16x8 hh;
#pragma unroll
                for (int q = 0; q < 4; ++q) {
                    hh[q] = (_Float16)nf[rt][0][q];
                    hh[q + 4] = (_Float16)nf[rt][1][q];
                }
                aC[set][rt] = hh;
            }
        }
    };

    // prologue: chunk 0 into set 0 / LDS buf 0
    stage(0, 0);
    prefetchA(0, 0);
    asm volatile("s_waitcnt vmcnt(0)" ::: "memory");
    __builtin_amdgcn_sched_barrier(0);
    commitA(0);
    __builtin_amdgcn_s_barrier();
    __builtin_amdgcn_sched_barrier(0);

#pragma unroll
    for (int c = 0; c < NCH; ++c) {
        const int b = c & 1;
        if (c + 1 < NCH) {
            stage(c + 1, b ^ 1);
            prefetchA(c + 1, b ^ 1);
            constexpr int VM = (NFRAG / 4) + (XIN ? 2 * RT : RT);
            asm volatile("s_waitcnt vmcnt(%0)" :: "i"(VM) : "memory");
        } else {
            asm volatile("s_waitcnt vmcnt(0)" ::: "memory");
        }
        __builtin_amdgcn_sched_barrier(0);
        __builtin_amdgcn_s_barrier();    // all waves' stage(c) visible
        __builtin_amdgcn_sched_barrier(0);

#pragma unroll
        for (int nt = 0; nt < NT; ++nt) {
            int ntf = h * NT + nt;
            h16x8 wh = s_w[b][ntf * 64 + lane];
            h16x8 wl = s_w[b][(NTT + ntf) * 64 + lane];
#pragma unroll
            for (int rt = 0; rt < RT; ++rt) {
                acc[rt][nt] = __builtin_amdgcn_mfma_f32_16x16x32_f16(aC[b][rt], wh, acc[rt][nt], 0, 0, 0);
                acc[rt][nt] = __builtin_amdgcn_mfma_f32_16x16x32_f16(aC[b][rt], wl, acc[rt][nt], 0, 0, 0);
            }
        }
        __builtin_amdgcn_sched_barrier(0);
        if (c + 1 < NCH) commitA(b ^ 1);   // XIN: convert landed fp32 -> f16
        __builtin_amdgcn_s_barrier();    // reads of buf b done before
                                         // stage(c+2) overwrites it
    }

    // C-write with rnorm prescale: col=lane&15 (=r), row=g*4+j per 16-tile
#pragma unroll
    for (int rt = 0; rt < RT; ++rt) {
        f32x4 rn4 = *(const f32x4*)&rnorm[row0 + rt * 16 + g * 4];
#pragma unroll
        for (int nt = 0; nt < NT; ++nt) {
            int ccol = (h * NT + nt) * 16 + r;
#pragma unroll
            for (int j = 0; j < 4; ++j) {
                int rr = row0 + rt * 16 + g * 4 + j;
                if (rr < n) out[(size_t)rr * DO + ccol] = (_Float16)(acc[rt][nt][j] * rn4[j]);
            }
        }
    }
}

extern "C" void kernel_launch(void* const* d_in, const int* in_sizes, int n_in,
                              void* d_out, int out_size, void* d_ws, size_t ws_size,
                              hipStream_t stream) {
    const float* X  = (const float*)d_in[0];
    const int* row  = (const int*)d_in[1];
    const int* col  = (const int*)d_in[2];
    const float* W0 = (const float*)d_in[3];
    const float* b0 = (const float*)d_in[4];
    const float* W1 = (const float*)d_in[5];
    const float* b1 = (const float*)d_in[6];
    const float* W2 = (const float*)d_in[7];
    const float* b2 = (const float*)d_in[8];

    int n = in_sizes[0] / 256;   // 100000
    int e = in_sizes[1];         // 1600000
    size_t n16pad = (size_t)((n + 15) / 16) * 16 + 128;   // tiled bufs padded

    char* ws = (char*)d_ws;
    size_t off = 0;
    auto alloc = [&](size_t bytes) {
        void* p = ws + off;
        off += (bytes + 255) & ~(size_t)255;
        return p;
    };
    _Float16* AT  = (_Float16*)alloc(n16pad * 256 * 2);   // tiled activations
    _Float16* Dh  = (_Float16*)alloc((size_t)n * 256 * 2);
    _Float16* W0h = (_Float16*)alloc(256 * 256 * 2);
    _Float16* W0l = (_Float16*)alloc(256 * 256 * 2);
    _Float16* W1h = (_Float16*)alloc(256 * 256 * 2);
    _Float16* W1l = (_Float16*)alloc(256 * 256 * 2);
    _Float16* W2h = (_Float16*)alloc(256 * 128 * 2);
    _Float16* W2l = (_Float16*)alloc(256 * 128 * 2);
    int*   cnt    = (int*)alloc((size_t)n * 4);
    int*   rank   = (int*)alloc((size_t)e * 4);
    float* rnorm  = (float*)alloc((size_t)n * 4 + 1024);  // +pad for OOB-safe f32x4
    int*   rowptr = (int*)alloc(((size_t)n + 1) * 4);
    int*   bsum   = (int*)alloc(512);
    int*   metac  = (int*)alloc((size_t)e * 4);

    (void)hipMemsetAsync(cnt, 0, (size_t)n * 4, stream);

    int gE = (e + 255) / 256;
    int gN = (n + 255) / 256;
    int nb = (n + 1023) / 1024;

    count_kernel<<<gE, 256, 0, stream>>>(row, cnt, rank, e);
    scan1_kernel<<<nb, 1024, 0, stream>>>(cnt, rowptr, bsum, rnorm, n);
    scan2_kernel<<<1, 128, 0, stream>>>(bsum, nb);
    scan3_kernel<<<gN, 256, 0, stream>>>(rowptr, bsum, n, e);
    fill_kernel<<<gE, 256, 0, stream>>>(row, col, rank, rowptr, metac, e);
    splitW_kernel<<<40960 / 256, 256, 0, stream>>>(W0, W1, W2, W0h, W0l, W1h, W1l, W2h, W2l);

    int gS  = (n + 7) / 8;        // spmm D=256: 4 waves x 2 rows
    int gS2 = (n + 15) / 16;      // spmm D=128: 4 waves x 4 rows
    int gMd = (n + 127) / 128;    // dense: BM=128 (RT=4)

    // D0' = R·(X @ W0T) ; A = gelu(rnorm*sum + b0) -> tiled f16
    dense_mfma_kernel<256, 4, true><<<gMd, 256, 0, stream>>>(nullptr, X, W0h, W0l, rnorm, Dh, n);
    spmm_kernel<256, true, true><<<gS, 256, 0, stream>>>(Dh, nullptr, AT, rowptr, metac, rnorm, b0, n);
    // D1' ; B -> tiled f16
    dense_mfma_kernel<256, 4, false><<<gMd, 256, 0, stream>>>(AT, nullptr, W1h, W1l, rnorm, Dh, n);
    spmm_kernel<256, true, true><<<gS, 256, 0, stream>>>(Dh, nullptr, AT, rowptr, metac, rnorm, b1, n);
    // D2' (128-wide) ; out = rnorm*sum + b2 (fp32), 4 rows/wave
    dense_mfma_kernel<128, 4, false><<<gMd, 256, 0, stream>>>(AT, nullptr, W2h, W2l, rnorm, Dh, n);
    spmm_kernel<128, false, false><<<gS2, 256, 0, stream>>>(Dh, (float*)d_out, nullptr, rowptr, metac, rnorm, b2, n);
}

// Round 23
// 573.659 us; speedup vs baseline: 1.0828x; 1.0828x over previous
//
#include <hip/hip_runtime.h>
#include <hip/hip_bf16.h>

// ---------------------------------------------------------------------------
// GCN via associativity:  spmm(H) @ W == spmm(H @ W)
//   D0 = X @ W0T   (f16)  ; A = gelu(spmm(D0) + b0) -> TILED f16
//   D1 = A @ W1T   (f16)  ; B = gelu(spmm(D1) + b1) -> TILED f16
//   D2 = B @ W2T   (f16)  ; out = spmm(D2) + b2     (fp32)
// Dense on MFMA: A single f16, W = f16 hi + f16 lo -> 2 MFMA products.
// SpMM: multi-row waves — every lane gathers 16B, lanes-per-row = D/8, so
// one gather instruction serves 2 edges (D=256) or 4 edges (D=128). The
// per-instruction TA cost is the binding constraint (round 20: 150->121µs);
// FETCH sits at the 402MB XCD-replication compulsory floor at ~4TB/s.
// CSR build rank-based (no fill atomics); dense0 reads X fp32 directly.
// (Round 22's weight-folding variant regressed — reverted to this form.)
// ---------------------------------------------------------------------------

typedef float f32x4 __attribute__((ext_vector_type(4)));
typedef float f32x2 __attribute__((ext_vector_type(2)));
typedef _Float16 h16x8 __attribute__((ext_vector_type(8)));
typedef _Float16 h16x4 __attribute__((ext_vector_type(4)));

__device__ __forceinline__ float gelu_fast(float x) {
    float u = 0.7978845608028654f * (x + 0.044715f * x * x * x);
    return x / (1.0f + __expf(-2.0f * u));
}

// count + per-edge rank (removes the fill-pass atomic)
__global__ void count_kernel(const int* __restrict__ row, int* __restrict__ cnt,
                             int* __restrict__ rank, int e) {
    int i = blockIdx.x * blockDim.x + threadIdx.x;
    if (i < e) rank[i] = atomicAdd(&cnt[row[i]], 1);
}

__global__ void rnorm_kernel(const int* __restrict__ cnt, float* __restrict__ rnorm, int n) {
    int i = blockIdx.x * blockDim.x + threadIdx.x;
    if (i < n) rnorm[i] = rsqrtf((float)(cnt[i] + 1));
}

__global__ void scan1_kernel(const int* __restrict__ cnt, int* __restrict__ rowptr,
                             int* __restrict__ bsum, int n) {
    __shared__ int s[1024];
    int t = threadIdx.x;
    int i = blockIdx.x * 1024 + t;
    int v = (i < n) ? cnt[i] : 0;
    s[t] = v;
    __syncthreads();
    for (int off = 1; off < 1024; off <<= 1) {
        int x = (t >= off) ? s[t - off] : 0;
        __syncthreads();
        s[t] += x;
        __syncthreads();
    }
    if (i < n) rowptr[i] = s[t] - v;
    if (t == 1023) bsum[blockIdx.x] = s[1023];
}

__global__ void scan2_kernel(int* bsum, int nb) {
    __shared__ int s[128];
    int t = threadIdx.x;
    int v = (t < nb) ? bsum[t] : 0;
    s[t] = v;
    __syncthreads();
    for (int off = 1; off < 128; off <<= 1) {
        int x = (t >= off) ? s[t - off] : 0;
        __syncthreads();
        s[t] += x;
        __syncthreads();
    }
    if (t < nb) bsum[t] = s[t] - v;   // exclusive
}

__global__ void scan3_kernel(int* __restrict__ rowptr, const int* __restrict__ bsum, int n, int e) {
    int i = blockIdx.x * blockDim.x + threadIdx.x;
    if (i < n) rowptr[i] += bsum[i >> 10];
    if (i == 0) rowptr[n] = e;
}

// atomic-free fill using precomputed ranks
__global__ void fill_kernel(const int* __restrict__ row, const int* __restrict__ col,
                            const int* __restrict__ rank,
                            const int* __restrict__ rowptr,
                            const float* __restrict__ rnorm,
                            int2* __restrict__ meta, int e) {
    int i = blockIdx.x * blockDim.x + threadIdx.x;
    if (i >= e) return;
    int r = row[i], c = col[i];
    int pos = rowptr[r] + rank[i];
    float w = rnorm[r] * rnorm[c];
    meta[pos] = make_int2(c, __float_as_int(w));
}

// fp32 -> (f16 hi, f16 lo) elementwise (weights only; 22-bit total)
__global__ void splitW_kernel(const float* __restrict__ in,
                              _Float16* __restrict__ hi,
                              _Float16* __restrict__ lo, int total4) {
    int i = blockIdx.x * blockDim.x + threadIdx.x;
    if (i >= total4) return;
    f32x4 x = *(const f32x4*)(in + (size_t)i * 4);
    h16x4 h, l;
#pragma unroll
    for (int q = 0; q < 4; ++q) {
        _Float16 hb = (_Float16)x[q];
        h[q] = hb;
        l[q] = (_Float16)(x[q] - (float)hb);
    }
    *(h16x4*)(hi + (size_t)i * 4) = h;
    *(h16x4*)(lo + (size_t)i * 4) = l;
}

// Multi-row waves: LPR = D/8 lanes per row (every lane gathers 16B = 8 f16);
// RPW = 64/LPR rows per wave (2 for D=256, 4 for D=128). One gather
// instruction serves RPW edges. 4-edge batches; tail via clamp + zero wt.
// Bias + optional gelu fused. SPLIT: LDS-assembled full-line tiled writes.
template <int D, bool GELU, bool SPLIT>
__global__ __launch_bounds__(256) void spmm_kernel(const _Float16* __restrict__ in,
                                                   float* __restrict__ out,
                                                   _Float16* __restrict__ oat,
                                                   const int* __restrict__ rowptr,
                                                   const int2* __restrict__ meta,
                                                   const float* __restrict__ rnorm,
                                                   const float* __restrict__ bias, int n) {
    constexpr int LPR = D / 8;           // lanes per row (32 / 16)
    constexpr int RPW = 64 / LPR;        // rows per wave  (2 / 4)
    constexpr int BR = 4 * RPW;          // rows per block (8 / 16)
    __shared__ _Float16 h_lds[8][256];   // used by SPLIT (D=256) only

    int t = threadIdx.x;
    int lane = t & 63;
    int w = t >> 6;
    int sub = lane % LPR;
    int rowsel = lane / LPR;
    int wid = blockIdx.x * BR + w * RPW + rowsel;
    if (wid >= n) wid = n - 1;           // safe clamp

    const _Float16* lanebase = in + sub * 8;
    float rn = rnorm[wid];
    float sw = rn * rn;                  // self-loop weight
    float acc[8];
    {
        h16x8 a = *(const h16x8*)(lanebase + (size_t)wid * D);
#pragma unroll
        for (int q = 0; q < 8; ++q) acc[q] = sw * (float)a[q];
    }

    int e0 = rowptr[wid], e1 = rowptr[wid + 1];
    int ne = e1 - e0;
    int maxb = (ne + 3) >> 2;
    int elast = (e1 > e0) ? (e1 - 1) : 0;

    int2 m[4];
    auto loadM = [&](int b) {
#pragma unroll
        for (int u = 0; u < 4; ++u) {
            int idx = e0 + b * 4 + u;
            int eu = idx < e1 ? idx : elast;
            int2 mm = meta[eu];
            if (idx >= e1) mm.y = 0;     // bits of 0.0f
            m[u] = mm;
        }
    };
    if (maxb > 0) loadM(0);
    for (int b = 0; b < maxb; ++b) {
        h16x8 v[4];
#pragma unroll
        for (int u = 0; u < 4; ++u)
            v[u] = *(const h16x8*)(lanebase + (size_t)m[u].x * D);
        float wts[4];
#pragma unroll
        for (int u = 0; u < 4; ++u) wts[u] = __int_as_float(m[u].y);
        if (b + 1 < maxb) loadM(b + 1);
#pragma unroll
        for (int u = 0; u < 4; ++u)
#pragma unroll
            for (int q = 0; q < 8; ++q) acc[q] = fmaf(wts[u], (float)v[u][q], acc[q]);
    }

    if (SPLIT) {
        // D=256 path (RPW=2): bias, gelu, stage row in LDS, tiled full-line write
        f32x4 bv0 = *(const f32x4*)(bias + sub * 8);
        f32x4 bv1 = *(const f32x4*)(bias + sub * 8 + 4);
        h16x8 h;
#pragma unroll
        for (int q = 0; q < 4; ++q) {
            float x0 = acc[q] + bv0[q];
            float x1 = acc[q + 4] + bv1[q];
            h[q] = (_Float16)(GELU ? gelu_fast(x0) : x0);
            h[q + 4] = (_Float16)(GELU ? gelu_fast(x1) : x1);
        }
        *(h16x8*)&h_lds[w * 2 + rowsel][sub * 8] = h;
        __syncthreads();
        // cooperative tiled write: thread -> (kc 0..7, g 0..3, j 0..7)
        int kc = t >> 5;                 // 0..7
        int g  = (t >> 3) & 3;           // 0..3
        int j  = t & 7;                  // 0..7 (row within block)
        size_t rg = (size_t)(blockIdx.x >> 1);
        int half = blockIdx.x & 1;       // 8-row half of the 16-row group
        size_t toff = ((rg * 8 + kc) * 64 + g * 16 + half * 8 + j) * 8;
        __builtin_nontemporal_store(*(const h16x8*)&h_lds[j][kc * 32 + g * 8],
                                    (h16x8*)(oat + toff));
    } else {
        f32x4 bv0 = *(const f32x4*)(bias + sub * 8);
        f32x4 bv1 = *(const f32x4*)(bias + sub * 8 + 4);
        f32x4 o0, o1;
#pragma unroll
        for (int q = 0; q < 4; ++q) {
            float x0 = acc[q] + bv0[q];
            float x1 = acc[q + 4] + bv1[q];
            o0[q] = GELU ? gelu_fast(x0) : x0;
            o1[q] = GELU ? gelu_fast(x1) : x1;
        }
        float* dst = out + (size_t)wid * D + sub * 8;
        __builtin_nontemporal_store(o0, (f32x4*)dst);
        __builtin_nontemporal_store(o1, (f32x4*)(dst + 4));
    }
}

// out[N][DO](f16) = A(f16) @ (Wh+Wl)(f16)^T via 2 f16 MFMAs.
// A source: XIN ? fp32 row-major X (in-register f16 convert) : tiled f16.
// COUNTED-vmcnt pipeline (T4), double-buffered LDS W staging.
template <int DO, int RT, bool XIN>
__global__ __launch_bounds__(256, 2) void dense_mfma_kernel(
        const _Float16* __restrict__ AT, const float* __restrict__ Xf,
        const _Float16* __restrict__ Whi, const _Float16* __restrict__ Wlo,
        _Float16* __restrict__ out, int n) {
    constexpr int KC = 32;
    constexpr int NCH = 256 / KC;        // 8 chunks
    constexpr int NTT = DO / 16;         // total col tiles (16 / 8)
    constexpr int NT = NTT / 2;          // col tiles per wave
    constexpr int NFRAG = 2 * NTT;       // Wh+Wl frags per chunk
    constexpr int BM = 2 * RT * 16;      // rows per block (128)
    __shared__ h16x8 s_w[2][NFRAG * 64]; // 2x32KB (DO=256) / 2x16KB (128)

    int t = threadIdx.x;
    int lane = t & 63;
    int w = t >> 6;
    int r = lane & 15;
    int g = lane >> 4;
    int h = w & 1;                       // col half
    int row0 = blockIdx.x * BM + (w >> 1) * (RT * 16);
    int n16 = (n + 15) >> 4;

    size_t argi[RT];                     // clamped row-group (tiled) or row (XIN)
#pragma unroll
    for (int rt = 0; rt < RT; ++rt) {
        if (XIN) {
            int arow = row0 + rt * 16 + r;
            if (arow >= n) arow = n - 1;
            argi[rt] = (size_t)arow;
        } else {
            int rg = (row0 >> 4) + rt;
            if (rg >= n16) rg = n16 - 1;
            argi[rt] = (size_t)rg;
        }
    }

    f32x4 acc[RT][NT];
#pragma unroll
    for (int rt = 0; rt < RT; ++rt)
#pragma unroll
        for (int nt = 0; nt < NT; ++nt) acc[rt][nt] = (f32x4){0.f, 0.f, 0.f, 0.f};

    auto stage = [&](int c, int b) {
#pragma unroll
        for (int i = 0; i < NFRAG / 4; ++i) {
            int s = t + i * 256;
            int sl = s & 63;
            int f = s >> 6;              // f = op*NTT + ntf
            int ntf = f % NTT;
            int op = f / NTT;
            const _Float16* src = op ? Wlo : Whi;
            const _Float16* gsrc =
                &src[(size_t)(ntf * 16 + (sl & 15)) * 256 + c * KC + ((sl >> 4) << 3)];
            __builtin_amdgcn_global_load_lds(
                (const __attribute__((address_space(1))) void*)gsrc,
                (__attribute__((address_space(3))) void*)&s_w[b][s], 16, 0, 0);
        }
    };

    h16x8 aC[2][RT];                     // 2-set A fragment file
    f32x4 nf[RT][2];                     // XIN raw fp32 in flight

    auto prefetchA = [&](int c, int set) {
#pragma unroll
        for (int rt = 0; rt < RT; ++rt) {
            if (XIN) {
                const float* src = &Xf[argi[rt] * 256 + c * KC + g * 8];
                nf[rt][0] = *(const f32x4*)src;
                nf[rt][1] = *(const f32x4*)(src + 4);
            } else {
                aC[set][rt] = *(const h16x8*)&AT[((argi[rt] * 8 + c) * 64 + lane) * 8];
            }
        }
    };
    auto commitA = [&](int set) {
        if (XIN) {
#pragma unroll
            for (int rt = 0; rt < RT; ++rt) {
                h16x8 hh;
#pragma unroll
                for (int q = 0; q < 4; ++q) {
                    hh[q] = (_Float16)nf[rt][0][q];
                    hh[q + 4] = (_Float16)nf[rt][1][q];
                }
                aC[set][rt] = hh;
            }
        }
    };

    // prologue: chunk 0 into set 0 / LDS buf 0
    stage(0, 0);
    prefetchA(0, 0);
    asm volatile("s_waitcnt vmcnt(0)" ::: "memory");
    __builtin_amdgcn_sched_barrier(0);
    commitA(0);
    __builtin_amdgcn_s_barrier();
    __builtin_amdgcn_sched_barrier(0);

#pragma unroll
    for (int c = 0; c < NCH; ++c) {
        const int b = c & 1;
        if (c + 1 < NCH) {
            stage(c + 1, b ^ 1);
            prefetchA(c + 1, b ^ 1);
            constexpr int VM = (NFRAG / 4) + (XIN ? 2 * RT : RT);
            asm volatile("s_waitcnt vmcnt(%0)" :: "i"(VM) : "memory");
        } else {
            asm volatile("s_waitcnt vmcnt(0)" ::: "memory");
        }
        __builtin_amdgcn_sched_barrier(0);
        __builtin_amdgcn_s_barrier();    // all waves' stage(c) visible
        __builtin_amdgcn_sched_barrier(0);

#pragma unroll
        for (int nt = 0; nt < NT; ++nt) {
            int ntf = h * NT + nt;
            h16x8 wh = s_w[b][ntf * 64 + lane];
            h16x8 wl = s_w[b][(NTT + ntf) * 64 + lane];
#pragma unroll
            for (int rt = 0; rt < RT; ++rt) {
                acc[rt][nt] = __builtin_amdgcn_mfma_f32_16x16x32_f16(aC[b][rt], wh, acc[rt][nt], 0, 0, 0);
                acc[rt][nt] = __builtin_amdgcn_mfma_f32_16x16x32_f16(aC[b][rt], wl, acc[rt][nt], 0, 0, 0);
            }
        }
        __builtin_amdgcn_sched_barrier(0);
        if (c + 1 < NCH) commitA(b ^ 1);   // XIN: convert landed fp32 -> f16
        __builtin_amdgcn_s_barrier();    // reads of buf b done before
                                         // stage(c+2) overwrites it
    }

    // C frag: col=lane&15 (=r), row=g*4+j within each 16-row tile
#pragma unroll
    for (int rt = 0; rt < RT; ++rt) {
#pragma unroll
        for (int nt = 0; nt < NT; ++nt) {
            int ccol = (h * NT + nt) * 16 + r;
#pragma unroll
            for (int j = 0; j < 4; ++j) {
                int rr = row0 + rt * 16 + g * 4 + j;
                if (rr < n) out[(size_t)rr * DO + ccol] = (_Float16)acc[rt][nt][j];
            }
        }
    }
}

extern "C" void kernel_launch(void* const* d_in, const int* in_sizes, int n_in,
                              void* d_out, int out_size, void* d_ws, size_t ws_size,
                              hipStream_t stream) {
    const float* X  = (const float*)d_in[0];
    const int* row  = (const int*)d_in[1];
    const int* col  = (const int*)d_in[2];
    const float* W0 = (const float*)d_in[3];
    const float* b0 = (const float*)d_in[4];
    const float* W1 = (const float*)d_in[5];
    const float* b1 = (const float*)d_in[6];
    const float* W2 = (const float*)d_in[7];
    const float* b2 = (const float*)d_in[8];

    int n = in_sizes[0] / 256;   // 100000
    int e = in_sizes[1];         // 1600000
    size_t n16pad = (size_t)((n + 15) / 16) * 16;   // tiled bufs padded

    char* ws = (char*)d_ws;
    size_t off = 0;
    auto alloc = [&](size_t bytes) {
        void* p = ws + off;
        off += (bytes + 255) & ~(size_t)255;
        return p;
    };
    _Float16* AT  = (_Float16*)alloc(n16pad * 256 * 2);   // tiled activations
    _Float16* Dh  = (_Float16*)alloc((size_t)n * 256 * 2);
    _Float16* W0h = (_Float16*)alloc(256 * 256 * 2);
    _Float16* W0l = (_Float16*)alloc(256 * 256 * 2);
    _Float16* W1h = (_Float16*)alloc(256 * 256 * 2);
    _Float16* W1l = (_Float16*)alloc(256 * 256 * 2);
    _Float16* W2h = (_Float16*)alloc(256 * 128 * 2);
    _Float16* W2l = (_Float16*)alloc(256 * 128 * 2);
    int*   cnt    = (int*)alloc((size_t)n * 4);
    int*   rank   = (int*)alloc((size_t)e * 4);
    float* rnorm  = (float*)alloc((size_t)n * 4);
    int*   rowptr = (int*)alloc(((size_t)n + 1) * 4);
    int*   bsum   = (int*)alloc(512);
    int2*  meta   = (int2*)alloc((size_t)e * 8);

    (void)hipMemsetAsync(cnt, 0, (size_t)n * 4, stream);

    int gE = (e + 255) / 256;
    int gN = (n + 255) / 256;
    int nb = (n + 1023) / 1024;

    count_kernel<<<gE, 256, 0, stream>>>(row, cnt, rank, e);
    rnorm_kernel<<<gN, 256, 0, stream>>>(cnt, rnorm, n);
    scan1_kernel<<<nb, 1024, 0, stream>>>(cnt, rowptr, bsum, n);
    scan2_kernel<<<1, 128, 0, stream>>>(bsum, nb);
    scan3_kernel<<<gN, 256, 0, stream>>>(rowptr, bsum, n, e);
    fill_kernel<<<gE, 256, 0, stream>>>(row, col, rank, rowptr, rnorm, meta, e);

    splitW_kernel<<<(16384 + 255) / 256, 256, 0, stream>>>(W0, W0h, W0l, 16384);
    splitW_kernel<<<(16384 + 255) / 256, 256, 0, stream>>>(W1, W1h, W1l, 16384);
    splitW_kernel<<<(8192 + 255) / 256, 256, 0, stream>>>(W2, W2h, W2l, 8192);

    int gS  = (n + 7) / 8;        // spmm D=256: 4 waves x 2 rows
    int gS2 = (n + 15) / 16;      // spmm D=128: 4 waves x 4 rows
    int gMd = (n + 127) / 128;    // dense: BM=128 (RT=4)

    // D0 = X @ W0T (X fp32 read + in-reg f16 convert) ; A -> tiled f16
    dense_mfma_kernel<256, 4, true><<<gMd, 256, 0, stream>>>(nullptr, X, W0h, W0l, Dh, n);
    spmm_kernel<256, true, true><<<gS, 256, 0, stream>>>(Dh, nullptr, AT, rowptr, meta, rnorm, b0, n);
    // D1 ; B = gelu(spmm(D1)+b1) -> tiled f16
    dense_mfma_kernel<256, 4, false><<<gMd, 256, 0, stream>>>(AT, nullptr, W1h, W1l, Dh, n);
    spmm_kernel<256, true, true><<<gS, 256, 0, stream>>>(Dh, nullptr, AT, rowptr, meta, rnorm, b1, n);
    // D2 (128-wide) ; out = spmm(D2) + b2 (fp32), 4 rows/wave
    dense_mfma_kernel<128, 4, false><<<gMd, 256, 0, stream>>>(AT, nullptr, W2h, W2l, Dh, n);
    spmm_kernel<128, false, false><<<gS2, 256, 0, stream>>>(Dh, (float*)d_out, nullptr, rowptr, meta, rnorm, b2, n);
}